// Round 7
// baseline (93.864 us; speedup 1.0000x reference)
//
#include <hip/hip_runtime.h>
#include <math.h>

#define N_BINS 256
#define TAU 0.01f
#define EPS 1e-10f
#define HW (512*512)
#define Q 4081            // quant levels; Q-1 = 4080 = 16*255 so t_q - b_j = (q-16j)/4080
#define QSTRIDE 4096
#define MWIN 208          // |q-16j| <= 208 -> dropped weight exp(-13) ~ 2e-6 (negligible)
#define WTAB (2*MWIN+1)   // 417
#define WPADN 432         // 16*27, zero-padded tail
#define NP 27             // taps per phase: m = 16*(p-13)+r
#define CFP_STRIDE 289    // odd stride -> 2-way bank aliasing only (free)
#define NPART 64          // hist partials per batch
#define MAGIC1 0x13572468u
#define MAGIC2 0x2468ACEFu   // ws poison is 0xAAAAAAAA -> never equals a magic

// One dispatch: hist -> flag barrier -> wide slice-reduce -> flag barrier ->
// per-block redundant conv/scan/LUT -> equalize register-held pixels.
// 256 blocks x 256 thr, 56 KB LDS -> co-resident (1 block/CU); no atomics, no memset.
__global__ __launch_bounds__(256) void fused_all(
    const float* __restrict__ x, float* __restrict__ part, float* __restrict__ c,
    unsigned int* __restrict__ flags1, unsigned int* __restrict__ flags2,
    float* __restrict__ out)
{
    __shared__ union { unsigned int lh[QSTRIDE]; float cfp[16 * CFP_STRIDE]; } U;
    __shared__ float ph[256 * 17];
    __shared__ float Tl[QSTRIDE];
    __shared__ float wtE[WPADN];
    __shared__ float cdfnp[288];
    __shared__ float onesp[288];
    __shared__ float red[256];
    __shared__ float wsum[4];
    __shared__ float h0s;

    const int tid = threadIdx.x;
    const int bid = blockIdx.x;
    const int b   = bid >> 6;
    const int s   = bid & 63;
    const int r   = tid & 15;
    const int t   = tid >> 4;        // 0..15

    // ---- Phase 1: load pixels (kept in registers), LDS hist, store partial ----
    const float4* xb = (const float4*)(x + (size_t)b * HW + (size_t)s * 4096);
    float4 px[4];
#pragma unroll
    for (int i = 0; i < 4; ++i) px[i] = xb[i * 256 + tid];

    for (int i = tid; i < QSTRIDE; i += 256) U.lh[i] = 0u;
    __syncthreads();
#pragma unroll
    for (int i = 0; i < 4; ++i) {
        const float4 v = px[i];
        int q0 = __float2int_rn(v.x * 4080.f);
        int q1 = __float2int_rn(v.y * 4080.f);
        int q2 = __float2int_rn(v.z * 4080.f);
        int q3 = __float2int_rn(v.w * 4080.f);
        q0 = min(max(q0, 0), Q - 1); q1 = min(max(q1, 0), Q - 1);
        q2 = min(max(q2, 0), Q - 1); q3 = min(max(q3, 0), Q - 1);
        atomicAdd(&U.lh[q0], 1u); atomicAdd(&U.lh[q1], 1u);
        atomicAdd(&U.lh[q2], 1u); atomicAdd(&U.lh[q3], 1u);
    }
    __syncthreads();
    {
        float4* pb = (float4*)(part + (size_t)bid * QSTRIDE);
#pragma unroll
        for (int k = 0; k < 4; ++k) {
            const int i4 = k * 256 + tid;
            pb[i4] = make_float4((float)U.lh[4 * i4], (float)U.lh[4 * i4 + 1],
                                 (float)U.lh[4 * i4 + 2], (float)U.lh[4 * i4 + 3]);
        }
    }
    __syncthreads();   // waves drain vmcnt at barrier; lh now dead
    if (tid == 0)
        __hip_atomic_store(&flags1[bid], MAGIC1, __ATOMIC_RELEASE, __HIP_MEMORY_SCOPE_AGENT);

    // ---- Overlap: LDS init for later phases while others finish phase 1 ----
    for (int i = tid; i < 16 * CFP_STRIDE; i += 256) U.cfp[i] = 0.f;
    for (int i = tid; i < 288; i += 256) {
        cdfnp[i] = 0.f;
        onesp[i] = (i >= 13 && i < 269) ? 1.f : 0.f;
    }
    for (int i = tid; i < WPADN; i += 256) {
        const float d = (float)(i - MWIN) * (1.0f / 4080.f);
        wtE[i] = (i < WTAB) ? __expf(-d * d * (1.0f / (2.0f * TAU * TAU))) : 0.f;
    }

    // ---- Barrier 1: wait for own batch's 64 partials ----
    if (tid < 64) {
        const unsigned int* f = &flags1[b * 64 + tid];
        while (__hip_atomic_load(f, __ATOMIC_RELAXED, __HIP_MEMORY_SCOPE_AGENT) != MAGIC1)
            __builtin_amdgcn_s_sleep(1);
    }
    __syncthreads();
    __builtin_amdgcn_fence(__ATOMIC_ACQUIRE, "agent");

    // ---- Phase 2: reduce own 64-bin slice across 64 partials -> c ----
    {
        const int qb = tid & 63;        // bin within slice
        const int pg = tid >> 6;        // partial group 0..3
        const unsigned int* pu = (const unsigned int*)part;
        float acc = 0.f;
#pragma unroll
        for (int k = 0; k < 16; ++k) {
            const int p = pg * 16 + k;
            const unsigned int raw = __hip_atomic_load(
                &pu[((size_t)(b * NPART + p)) * QSTRIDE + s * 64 + qb],
                __ATOMIC_RELAXED, __HIP_MEMORY_SCOPE_AGENT);
            acc += __uint_as_float(raw);
        }
        red[tid] = acc;
    }
    __syncthreads();
    if (tid < 64)
        c[(size_t)b * QSTRIDE + s * 64 + tid] =
            red[tid] + red[tid + 64] + red[tid + 128] + red[tid + 192];
    __syncthreads();   // drains the c stores
    if (tid == 0)
        __hip_atomic_store(&flags2[bid], MAGIC2, __ATOMIC_RELEASE, __HIP_MEMORY_SCOPE_AGENT);

    // ---- Barrier 2: wait for own batch's merged counts ----
    if (tid < 64) {
        const unsigned int* f = &flags2[b * 64 + tid];
        while (__hip_atomic_load(f, __ATOMIC_RELAXED, __HIP_MEMORY_SCOPE_AGENT) != MAGIC2)
            __builtin_amdgcn_s_sleep(1);
    }
    __syncthreads();
    __builtin_amdgcn_fence(__ATOMIC_ACQUIRE, "agent");

    // ---- Phase 3a: load merged counts (16 KB), scatter phase-transposed ----
    {
        const unsigned int* cu = (const unsigned int*)(c + (size_t)b * QSTRIDE);
#pragma unroll
        for (int k = 0; k < 16; ++k) {
            const int q = k * 256 + tid;
            const unsigned int raw =
                __hip_atomic_load(&cu[q], __ATOMIC_RELAXED, __HIP_MEMORY_SCOPE_AGENT);
            U.cfp[(q & 15) * CFP_STRIDE + (q >> 4) + 13] = __uint_as_float(raw);
        }
    }
    __syncthreads();

    // ---- Phase 3b: conv, register-blocked per (r, t): hist[j]=sum wt*cnt ----
    {
        float creg[42];
        const float* cbase = &U.cfp[r * CFP_STRIDE + 16 * t];
#pragma unroll
        for (int k = 0; k < 42; ++k) creg[k] = cbase[k];
        float acc[16];
#pragma unroll
        for (int uu = 0; uu < 16; ++uu) acc[uu] = 0.f;
#pragma unroll
        for (int p = 0; p < NP; ++p) {
            const float w = wtE[16 * p + r];
#pragma unroll
            for (int uu = 0; uu < 16; ++uu) acc[uu] += w * creg[uu + p];
        }
#pragma unroll
        for (int uu = 0; uu < 16; ++uu) ph[(16 * t + uu) * 17 + r] = acc[uu];
    }
    __syncthreads();

    // ---- Phase 3c: phase-reduce + wave-shuffle scan + cdf normalization ----
    float hv = 0.f;
#pragma unroll
    for (int rr = 0; rr < 16; ++rr) hv += ph[tid * 17 + rr];
    float val = hv;
    const int lane = tid & 63;
#pragma unroll
    for (int d = 1; d < 64; d <<= 1) {
        const float n = __shfl_up(val, (unsigned)d, 64);
        if (lane >= d) val += n;
    }
    if (lane == 63) wsum[tid >> 6] = val;
    if (tid == 0) h0s = hv;
    __syncthreads();
    {
        float prefix = 0.f, total = 0.f;
#pragma unroll
        for (int w2 = 0; w2 < 4; ++w2) {
            const float ws = wsum[w2];
            if (w2 < (tid >> 6)) prefix += ws;
            total += ws;
        }
        val += prefix;
        const float inv  = 1.0f / (total + EPS);
        const float cdf0 = h0s * inv;
        cdfnp[tid + 13] = (val * inv - cdf0) / (1.0f - cdf0 + EPS);
    }
    __syncthreads();

    // ---- Phase 3d: output LUT, register-blocked per (r, t) ----
    {
        float creg[42], oreg[42];
        const int base = 16 * t;
#pragma unroll
        for (int k = 0; k < 42; ++k) { creg[k] = cdfnp[base + k]; oreg[k] = onesp[base + k]; }
        float acc[16], sw[16];
#pragma unroll
        for (int uu = 0; uu < 16; ++uu) { acc[uu] = 0.f; sw[uu] = 0.f; }
#pragma unroll
        for (int p = 0; p < NP; ++p) {
            const float w = wtE[16 * p + r];
#pragma unroll
            for (int uu = 0; uu < 16; ++uu) {
                const int k = uu - p + 26;   // in [0,42)
                acc[uu] += w * creg[k];
                sw[uu]  += w * oreg[k];
            }
        }
#pragma unroll
        for (int uu = 0; uu < 16; ++uu)
            Tl[16 * (16 * t + uu) + r] = acc[uu] / (sw[uu] + EPS);
    }
    __syncthreads();

    // ---- Phase 4: equalize register-held pixels via LUT lerp ----
    float4* ob = (float4*)(out + (size_t)b * HW + (size_t)s * 4096);
#pragma unroll
    for (int i = 0; i < 4; ++i) {
        const float4 v = px[i];
        const float vv[4] = {v.x, v.y, v.z, v.w};
        float res[4];
#pragma unroll
        for (int k2 = 0; k2 < 4; ++k2) {
            const float u = vv[k2] * 4080.f;
            int q = (int)u;
            q = min(max(q, 0), Q - 2);
            const float frac = u - (float)q;
            const float t0 = Tl[q], t1 = Tl[q + 1];
            res[k2] = fmaf(frac, t1 - t0, t0);
        }
        ob[i * 256 + tid] = make_float4(res[0], res[1], res[2], res[3]);
    }
}

extern "C" void kernel_launch(void* const* d_in, const int* in_sizes, int n_in,
                              void* d_out, int out_size, void* d_ws, size_t ws_size,
                              hipStream_t stream) {
    const float* x = (const float*)d_in[0];
    float* out     = (float*)d_out;
    const int B    = in_sizes[0] / HW;   // = 4
    const int nblk = 64 * B;             // 256 blocks <= 256 CUs -> co-resident

    float* part          = (float*)d_ws;                            // B*64*4096 floats (4 MB)
    float* c             = part + (size_t)B * NPART * QSTRIDE;      // B*4096 floats
    unsigned int* flags1 = (unsigned int*)(c + (size_t)B * QSTRIDE);
    unsigned int* flags2 = flags1 + nblk;
    // flags need no init: ws is re-poisoned to 0xAAAAAAAA before every launch,
    // which never equals MAGIC1/MAGIC2.

    fused_all<<<nblk, 256, 0, stream>>>(x, part, c, flags1, flags2, out);
}

// Round 8
// 64.937 us; speedup vs baseline: 1.4455x; 1.4455x over previous
//
#include <hip/hip_runtime.h>
#include <math.h>

#define N_BINS 256
#define TAU 0.01f
#define EPS 1e-10f
#define HW (512*512)
#define Q 4081            // quant levels; Q-1 = 4080 = 16*255 so t_q - b_j = (q-16j)/4080
#define QSTRIDE 4096
#define MWIN 208          // |q-16j| <= 208 -> dropped weight exp(-13) ~ 2e-6 (negligible)
#define WTAB (2*MWIN+1)   // 417
#define WPADN 432         // 16*27, zero-padded tail
#define NP 27             // taps per phase: m = 16*(p-13)+r
#define CFP_STRIDE 289    // odd stride -> 2-way bank aliasing only (free)
#define NPART 64          // partial soft-hists per batch

// -------- K1: fine hist -> register-blocked conv -> 256-float soft partial --------
// grid (64, B) x 256 thr. Conv is linear: sum of partial convs == conv of summed hist.
__global__ __launch_bounds__(256) void hist_conv_kernel(const float* __restrict__ x,
                                                        float* __restrict__ partT) {
    __shared__ float cfp[16 * CFP_STRIDE];                            // 18.5 KB
    __shared__ union { unsigned int lh[QSTRIDE]; float ph[256 * 17]; } U;  // 17.4 KB
    __shared__ float wtE[WPADN];
    const int b   = blockIdx.y;
    const int s   = blockIdx.x;
    const int tid = threadIdx.x;
    const int r   = tid & 15;
    const int t   = tid >> 4;        // 0..15

    for (int i = tid; i < QSTRIDE; i += 256) U.lh[i] = 0u;
    for (int i = tid; i < 16 * CFP_STRIDE; i += 256) cfp[i] = 0.f;
    for (int i = tid; i < WPADN; i += 256) {
        const float d = (float)(i - MWIN) * (1.0f / 4080.f);
        wtE[i] = (i < WTAB) ? __expf(-d * d * (1.0f / (2.0f * TAU * TAU))) : 0.f;
    }
    __syncthreads();

    const float4* xb = (const float4*)(x + (size_t)b * HW + (size_t)s * 4096);
#pragma unroll
    for (int i = 0; i < 4; ++i) {
        const float4 v = xb[i * 256 + tid];
        int q0 = __float2int_rn(v.x * 4080.f);
        int q1 = __float2int_rn(v.y * 4080.f);
        int q2 = __float2int_rn(v.z * 4080.f);
        int q3 = __float2int_rn(v.w * 4080.f);
        q0 = min(max(q0, 0), Q - 1); q1 = min(max(q1, 0), Q - 1);
        q2 = min(max(q2, 0), Q - 1); q3 = min(max(q3, 0), Q - 1);
        atomicAdd(&U.lh[q0], 1u); atomicAdd(&U.lh[q1], 1u);
        atomicAdd(&U.lh[q2], 1u); atomicAdd(&U.lh[q3], 1u);
    }
    __syncthreads();

    // scatter fine hist phase-transposed into cfp (pads stay zero)
#pragma unroll
    for (int k = 0; k < 16; ++k) {
        const int q = k * 256 + tid;
        cfp[(q & 15) * CFP_STRIDE + (q >> 4) + 13] = (float)U.lh[q];
    }
    __syncthreads();

    // conv: hist[j] = sum_r sum_p wtE[16p+r] * cnt[16(j+p-13)+r]; thread (r,t): 16 bins
    {
        float creg[42];
        const float* cbase = &cfp[r * CFP_STRIDE + 16 * t];
#pragma unroll
        for (int k = 0; k < 42; ++k) creg[k] = cbase[k];
        float acc[16];
#pragma unroll
        for (int uu = 0; uu < 16; ++uu) acc[uu] = 0.f;
#pragma unroll
        for (int p = 0; p < NP; ++p) {
            const float w = wtE[16 * p + r];
#pragma unroll
            for (int uu = 0; uu < 16; ++uu) acc[uu] += w * creg[uu + p];
        }
#pragma unroll
        for (int uu = 0; uu < 16; ++uu) U.ph[(16 * t + uu) * 17 + r] = acc[uu];
    }
    __syncthreads();

    // phase-reduce -> partial soft hist value for bin `tid`; transposed store:
    // partT[b][bin][s] so K2 reads its bin's 64 partials as 16 contiguous float4
    float hv = 0.f;
#pragma unroll
    for (int rr = 0; rr < 16; ++rr) hv += U.ph[tid * 17 + rr];
    partT[(size_t)b * (NPART * N_BINS) + (size_t)tid * NPART + s] = hv;
}

// -------- K2: reduce partials -> scan -> LUT -> equalize (all in one, 256-wide) --------
// grid (64, B) x 256 thr. Dispatch boundary = the global barrier (HW, ~3 us).
__global__ __launch_bounds__(256) void lut_equalize_kernel(const float* __restrict__ x,
                                                           const float* __restrict__ partT,
                                                           float* __restrict__ out) {
    __shared__ float Tl[QSTRIDE];            // 16 KB
    __shared__ float wtE[WPADN];
    __shared__ float cdfnp[288];
    __shared__ float onesp[288];
    __shared__ float wsum[4];
    __shared__ float h0s;
    const int b   = blockIdx.y;
    const int s   = blockIdx.x;
    const int tid = threadIdx.x;
    const int r   = tid & 15;
    const int t   = tid >> 4;        // 0..15

    for (int i = tid; i < 288; i += 256) {
        cdfnp[i] = 0.f;
        onesp[i] = (i >= 13 && i < 269) ? 1.f : 0.f;
    }
    for (int i = tid; i < WPADN; i += 256) {
        const float d = (float)(i - MWIN) * (1.0f / 4080.f);
        wtE[i] = (i < WTAB) ? __expf(-d * d * (1.0f / (2.0f * TAU * TAU))) : 0.f;
    }

    // pixel loads issued early (independent of the reduction)
    const float4* xb = (const float4*)(x + (size_t)b * HW + (size_t)s * 4096);
    float4 px[4];
#pragma unroll
    for (int i = 0; i < 4; ++i) px[i] = xb[i * 256 + tid];

    // reduce bin `tid` across 64 partials: 16 contiguous float4 (L2-hot, 64 KB/block)
    const float4* pT = (const float4*)(partT + (size_t)b * (NPART * N_BINS) +
                                       (size_t)tid * NPART);
    float4 a4 = make_float4(0.f, 0.f, 0.f, 0.f);
#pragma unroll
    for (int k = 0; k < 16; ++k) {
        const float4 v = pT[k];
        a4.x += v.x; a4.y += v.y; a4.z += v.z; a4.w += v.w;
    }
    const float hv = (a4.x + a4.y) + (a4.z + a4.w);

    // wave-shuffle inclusive scan over 256 bins + cdf normalization
    float val = hv;
    const int lane = tid & 63;
#pragma unroll
    for (int d = 1; d < 64; d <<= 1) {
        const float n = __shfl_up(val, (unsigned)d, 64);
        if (lane >= d) val += n;
    }
    if (lane == 63) wsum[tid >> 6] = val;
    if (tid == 0) h0s = hv;
    __syncthreads();
    {
        float prefix = 0.f, total = 0.f;
#pragma unroll
        for (int w2 = 0; w2 < 4; ++w2) {
            const float ws = wsum[w2];
            if (w2 < (tid >> 6)) prefix += ws;
            total += ws;
        }
        val += prefix;
        const float inv  = 1.0f / (total + EPS);
        const float cdf0 = h0s * inv;
        cdfnp[tid + 13] = (val * inv - cdf0) / (1.0f - cdf0 + EPS);
    }
    __syncthreads();

    // output LUT, register-blocked per (r, t)
    {
        float creg[42], oreg[42];
        const int base = 16 * t;
#pragma unroll
        for (int k = 0; k < 42; ++k) { creg[k] = cdfnp[base + k]; oreg[k] = onesp[base + k]; }
        float acc[16], sw[16];
#pragma unroll
        for (int uu = 0; uu < 16; ++uu) { acc[uu] = 0.f; sw[uu] = 0.f; }
#pragma unroll
        for (int p = 0; p < NP; ++p) {
            const float w = wtE[16 * p + r];
#pragma unroll
            for (int uu = 0; uu < 16; ++uu) {
                const int k = uu - p + 26;   // in [0,42)
                acc[uu] += w * creg[k];
                sw[uu]  += w * oreg[k];
            }
        }
#pragma unroll
        for (int uu = 0; uu < 16; ++uu)
            Tl[16 * (16 * t + uu) + r] = acc[uu] / (sw[uu] + EPS);
    }
    __syncthreads();

    // equalize register-held pixels via LUT lerp
    float4* ob = (float4*)(out + (size_t)b * HW + (size_t)s * 4096);
#pragma unroll
    for (int i = 0; i < 4; ++i) {
        const float4 v = px[i];
        const float vv[4] = {v.x, v.y, v.z, v.w};
        float res[4];
#pragma unroll
        for (int k2 = 0; k2 < 4; ++k2) {
            const float u = vv[k2] * 4080.f;
            int q = (int)u;
            q = min(max(q, 0), Q - 2);
            const float frac = u - (float)q;
            const float t0 = Tl[q], t1 = Tl[q + 1];
            res[k2] = fmaf(frac, t1 - t0, t0);
        }
        ob[i * 256 + tid] = make_float4(res[0], res[1], res[2], res[3]);
    }
}

extern "C" void kernel_launch(void* const* d_in, const int* in_sizes, int n_in,
                              void* d_out, int out_size, void* d_ws, size_t ws_size,
                              hipStream_t stream) {
    const float* x = (const float*)d_in[0];
    float* out     = (float*)d_out;
    const int B    = in_sizes[0] / HW;   // = 4

    float* partT = (float*)d_ws;         // B*256*64 floats = 256 KB, plain stores (no memset)

    hist_conv_kernel<<<dim3(NPART, B), 256, 0, stream>>>(x, partT);
    lut_equalize_kernel<<<dim3(NPART, B), 256, 0, stream>>>(x, partT, out);
}

// Round 10
// 61.674 us; speedup vs baseline: 1.5219x; 1.0529x over previous
//
#include <hip/hip_runtime.h>
#include <math.h>

#define N_BINS 256
#define TAU 0.01f
#define EPS 1e-10f
#define HW (512*512)
#define Q 4081            // quant levels; Q-1 = 4080 = 16*255 so t_q - b_j = (q-16j)/4080
#define QSTRIDE 4096
#define MWIN 208          // |q-16j| <= 208 -> dropped weight exp(-13) ~ 2e-6 (negligible)
#define WTAB (2*MWIN+1)   // 417
#define WPADN 432         // 16*27, zero-padded tail
#define NP 27             // taps per phase: m = 16*(p-13)+r
#define CFP_STRIDE 289    // odd stride -> 2-way bank aliasing only (free)
#define NPART 64          // partial soft-hists per batch
#define REDS 260          // red row stride (floats); 260*4 bytes is 16B-aligned

// -------- K1: fine hist -> register-blocked conv -> 256-float soft partial --------
// grid (64,B) x 512 thr (8 waves/CU). Conv linearity: partial convs sum to full conv.
__global__ __launch_bounds__(512) void hist_conv_kernel(const float* __restrict__ x,
                                                        float* __restrict__ partT) {
    __shared__ float cfp[16 * CFP_STRIDE];                            // 18.5 KB
    __shared__ union { unsigned int lh[QSTRIDE]; float ph[256 * 17]; } U;  // 17.4 KB
    __shared__ float wtE[WPADN];
    const int b   = blockIdx.y;
    const int s   = blockIdx.x;
    const int tid = threadIdx.x;
    const int r   = tid & 15;
    const int t   = tid >> 4;        // 0..31 -> 8 bins each

    for (int i = tid; i < QSTRIDE; i += 512) U.lh[i] = 0u;
    for (int i = tid; i < 16 * CFP_STRIDE; i += 512) cfp[i] = 0.f;
    for (int i = tid; i < WPADN; i += 512) {
        const float d = (float)(i - MWIN) * (1.0f / 4080.f);
        wtE[i] = (i < WTAB) ? __expf(-d * d * (1.0f / (2.0f * TAU * TAU))) : 0.f;
    }
    __syncthreads();

    const float4* xb = (const float4*)(x + (size_t)b * HW + (size_t)s * 4096);
#pragma unroll
    for (int i = 0; i < 2; ++i) {
        const float4 v = xb[i * 512 + tid];
        int q0 = __float2int_rn(v.x * 4080.f);
        int q1 = __float2int_rn(v.y * 4080.f);
        int q2 = __float2int_rn(v.z * 4080.f);
        int q3 = __float2int_rn(v.w * 4080.f);
        q0 = min(max(q0, 0), Q - 1); q1 = min(max(q1, 0), Q - 1);
        q2 = min(max(q2, 0), Q - 1); q3 = min(max(q3, 0), Q - 1);
        atomicAdd(&U.lh[q0], 1u); atomicAdd(&U.lh[q1], 1u);
        atomicAdd(&U.lh[q2], 1u); atomicAdd(&U.lh[q3], 1u);
    }
    __syncthreads();

    // scatter fine hist phase-transposed into cfp (pads stay zero)
#pragma unroll
    for (int k = 0; k < 8; ++k) {
        const int q = k * 512 + tid;
        cfp[(q & 15) * CFP_STRIDE + (q >> 4) + 13] = (float)U.lh[q];
    }
    __syncthreads();

    // conv: thread (r,t) computes bins 8t..8t+7 for phase r
    {
        float creg[34];
        const float* cbase = &cfp[r * CFP_STRIDE + 8 * t];
#pragma unroll
        for (int k = 0; k < 34; ++k) creg[k] = cbase[k];
        float acc[8];
#pragma unroll
        for (int uu = 0; uu < 8; ++uu) acc[uu] = 0.f;
#pragma unroll
        for (int p = 0; p < NP; ++p) {
            const float w = wtE[16 * p + r];
#pragma unroll
            for (int uu = 0; uu < 8; ++uu) acc[uu] += w * creg[uu + p];
        }
#pragma unroll
        for (int uu = 0; uu < 8; ++uu) U.ph[(8 * t + uu) * 17 + r] = acc[uu];
    }
    __syncthreads();

    // phase-reduce -> coalesced store: partT[b][s][bin]
    if (tid < N_BINS) {
        float hv = 0.f;
#pragma unroll
        for (int rr = 0; rr < 16; ++rr) hv += U.ph[tid * 17 + rr];
        partT[((size_t)b * NPART + s) * N_BINS + tid] = hv;
    }
}

// -------- K2: coalesced reduce -> scan -> LUT -> equalize --------
// grid (64,B) x 512 thr. Dispatch boundary = the device-wide barrier (HW, cheap).
__global__ __launch_bounds__(512) void lut_equalize_kernel(const float* __restrict__ x,
                                                           const float* __restrict__ partT,
                                                           float* __restrict__ out) {
    __shared__ float Tl[QSTRIDE];                    // 16 KB
    __shared__ float wtE[WPADN];
    __shared__ float cdfnp[288];
    __shared__ float onesp[288];
    __shared__ __align__(16) float red[8 * REDS];    // 8.3 KB, padded rows
    __shared__ float wsum[4];
    __shared__ float h0s;
    const int b    = blockIdx.y;
    const int s    = blockIdx.x;
    const int tid  = threadIdx.x;
    const int r    = tid & 15;
    const int t    = tid >> 4;       // 0..31
    const int wv   = tid >> 6;       // wave 0..7
    const int lane = tid & 63;

    // full-coverage init loops (round-9 bug: offset indexing left wtE[224..431] garbage)
    for (int i = tid; i < 288; i += 512) {
        cdfnp[i] = 0.f;
        onesp[i] = (i >= 13 && i < 269) ? 1.f : 0.f;
    }
    for (int i = tid; i < WPADN; i += 512) {
        const float d = (float)(i - MWIN) * (1.0f / 4080.f);
        wtE[i] = (i < WTAB) ? __expf(-d * d * (1.0f / (2.0f * TAU * TAU))) : 0.f;
    }

    // pixel loads issued early (independent of the reduction)
    const float4* xb = (const float4*)(x + (size_t)b * HW + (size_t)s * 4096);
    float4 px[2];
#pragma unroll
    for (int i = 0; i < 2; ++i) px[i] = xb[i * 512 + tid];

    // reduce 64x256 partial matrix: wave wv sums rows 8wv..8wv+7 (lane-contiguous float4)
    {
        const float4* base4 = (const float4*)(partT + (size_t)b * NPART * N_BINS);
        float4 a4 = make_float4(0.f, 0.f, 0.f, 0.f);
#pragma unroll
        for (int rr = 0; rr < 8; ++rr) {
            const float4 v = base4[(size_t)(8 * wv + rr) * 64 + lane];
            a4.x += v.x; a4.y += v.y; a4.z += v.z; a4.w += v.w;
        }
        ((float4*)&red[wv * REDS])[lane] = a4;
    }
    __syncthreads();

    // cross-wave reduce + wave-shuffle scan over 256 bins + cdf normalization
    float val = 0.f, hv = 0.f;
    if (tid < N_BINS) {
#pragma unroll
        for (int w2 = 0; w2 < 8; ++w2) hv += red[w2 * REDS + tid];
        val = hv;
#pragma unroll
        for (int d = 1; d < 64; d <<= 1) {
            const float n = __shfl_up(val, (unsigned)d, 64);
            if (lane >= d) val += n;
        }
        if (lane == 63) wsum[tid >> 6] = val;
        if (tid == 0) h0s = hv;
    }
    __syncthreads();
    if (tid < N_BINS) {
        float prefix = 0.f, total = 0.f;
#pragma unroll
        for (int w2 = 0; w2 < 4; ++w2) {
            const float ws = wsum[w2];
            if (w2 < (tid >> 6)) prefix += ws;
            total += ws;
        }
        val += prefix;
        const float inv  = 1.0f / (total + EPS);
        const float cdf0 = h0s * inv;
        cdfnp[tid + 13] = (val * inv - cdf0) / (1.0f - cdf0 + EPS);
    }
    __syncthreads();

    // output LUT: thread (r,t) computes T[16u+r] for u = 8t..8t+7
    {
        float creg[34], oreg[34];
        const int base = 8 * t;
#pragma unroll
        for (int k = 0; k < 34; ++k) { creg[k] = cdfnp[base + k]; oreg[k] = onesp[base + k]; }
        float acc[8], sw[8];
#pragma unroll
        for (int uu = 0; uu < 8; ++uu) { acc[uu] = 0.f; sw[uu] = 0.f; }
#pragma unroll
        for (int p = 0; p < NP; ++p) {
            const float w = wtE[16 * p + r];
#pragma unroll
            for (int uu = 0; uu < 8; ++uu) {
                const int k = uu - p + 26;   // in [0,34)
                acc[uu] += w * creg[k];
                sw[uu]  += w * oreg[k];
            }
        }
#pragma unroll
        for (int uu = 0; uu < 8; ++uu)
            Tl[16 * (8 * t + uu) + r] = acc[uu] / (sw[uu] + EPS);
    }
    __syncthreads();

    // equalize register-held pixels via LUT lerp
    float4* ob = (float4*)(out + (size_t)b * HW + (size_t)s * 4096);
#pragma unroll
    for (int i = 0; i < 2; ++i) {
        const float4 v = px[i];
        const float vv[4] = {v.x, v.y, v.z, v.w};
        float res[4];
#pragma unroll
        for (int k2 = 0; k2 < 4; ++k2) {
            const float u = vv[k2] * 4080.f;
            int q = (int)u;
            q = min(max(q, 0), Q - 2);
            const float frac = u - (float)q;
            const float t0 = Tl[q], t1 = Tl[q + 1];
            res[k2] = fmaf(frac, t1 - t0, t0);
        }
        ob[i * 512 + tid] = make_float4(res[0], res[1], res[2], res[3]);
    }
}

extern "C" void kernel_launch(void* const* d_in, const int* in_sizes, int n_in,
                              void* d_out, int out_size, void* d_ws, size_t ws_size,
                              hipStream_t stream) {
    const float* x = (const float*)d_in[0];
    float* out     = (float*)d_out;
    const int B    = in_sizes[0] / HW;   // = 4

    float* partT = (float*)d_ws;         // B*64*256 floats = 256 KB, plain stores (no memset)

    hist_conv_kernel<<<dim3(NPART, B), 512, 0, stream>>>(x, partT);
    lut_equalize_kernel<<<dim3(NPART, B), 512, 0, stream>>>(x, partT, out);
}